// Round 4
// baseline (351.489 us; speedup 1.0000x reference)
//
#include <hip/hip_runtime.h>
#include <math.h>

// Problem constants (from reference setup_inputs)
constexpr int B = 64, T = 2000, C = 100, K = 200, D = 2048;
constexpr float ALPHA = 0.0005f, BETA = 0.2f, LMBD = 1.0f, MARGIN = 100.0f, THRES = 0.5f;

constexpr int TT    = 25;          // sup time tiles: grid = 64*25 = 1600 blocks
constexpr int TTILE = T / TT;      // 80 rows per tile

// ---------------------------------------------------------------------------
// Kernel 1: partial sums over K rows of feat.
// Block = (tensor, split, dhalf, b): 256 threads, each owns ONE float4 slot of
// a half-row (1024 floats). kq rows per split, 8 loads in flight per thread.
// grid = 2 * ksplit * 2 * B  (ksplit=8 -> 2048 blocks = 8/CU, full occupancy).
// ---------------------------------------------------------------------------
__global__ __launch_bounds__(256) void feat_sum_kernel(const float* __restrict__ feat_act,
                                                       const float* __restrict__ feat_bkg,
                                                       float* __restrict__ meanpart,
                                                       int ksplit, int kq) {
    int t = blockIdx.x;
    const int b     = t & 63;  t >>= 6;
    const int dhalf = t & 1;   t >>= 1;
    const int split = t % ksplit;
    const int tensor = t / ksplit;

    const float* __restrict__ feat = (tensor == 0) ? feat_act : feat_bkg;
    const float* p = feat + (size_t)b * K * D + (size_t)split * kq * D
                     + (size_t)dhalf * 1024 + (size_t)threadIdx.x * 4;

    float4 a0 = make_float4(0.f, 0.f, 0.f, 0.f);
    float4 a1 = make_float4(0.f, 0.f, 0.f, 0.f);
    float4 a2 = make_float4(0.f, 0.f, 0.f, 0.f);
    float4 a3 = make_float4(0.f, 0.f, 0.f, 0.f);

    int k = 0;
    for (; k + 8 <= kq; k += 8) {
        float4 v0 = *(const float4*)(p + (size_t)(k + 0) * D);
        float4 v1 = *(const float4*)(p + (size_t)(k + 1) * D);
        float4 v2 = *(const float4*)(p + (size_t)(k + 2) * D);
        float4 v3 = *(const float4*)(p + (size_t)(k + 3) * D);
        float4 v4 = *(const float4*)(p + (size_t)(k + 4) * D);
        float4 v5 = *(const float4*)(p + (size_t)(k + 5) * D);
        float4 v6 = *(const float4*)(p + (size_t)(k + 6) * D);
        float4 v7 = *(const float4*)(p + (size_t)(k + 7) * D);
        a0.x += v0.x; a0.y += v0.y; a0.z += v0.z; a0.w += v0.w;
        a1.x += v1.x; a1.y += v1.y; a1.z += v1.z; a1.w += v1.w;
        a2.x += v2.x; a2.y += v2.y; a2.z += v2.z; a2.w += v2.w;
        a3.x += v3.x; a3.y += v3.y; a3.z += v3.z; a3.w += v3.w;
        a0.x += v4.x; a0.y += v4.y; a0.z += v4.z; a0.w += v4.w;
        a1.x += v5.x; a1.y += v5.y; a1.z += v5.z; a1.w += v5.w;
        a2.x += v6.x; a2.y += v6.y; a2.z += v6.z; a2.w += v6.w;
        a3.x += v7.x; a3.y += v7.y; a3.z += v7.z; a3.w += v7.w;
    }
    for (; k < kq; ++k) {
        float4 v = *(const float4*)(p + (size_t)k * D);
        a0.x += v.x; a0.y += v.y; a0.z += v.z; a0.w += v.w;
    }

    float4 s;
    s.x = (a0.x + a1.x) + (a2.x + a3.x);
    s.y = (a0.y + a1.y) + (a2.y + a3.y);
    s.z = (a0.z + a1.z) + (a2.z + a3.z);
    s.w = (a0.w + a1.w) + (a2.w + a3.w);

    float* dst = meanpart + ((size_t)((tensor * ksplit + split) * B + b)) * D
                 + (size_t)dhalf * 1024 + (size_t)threadIdx.x * 4;
    *(float4*)dst = s;
}

// ---------------------------------------------------------------------------
// Kernel 2: per-(tensor, b): combine ksplit partials, mean (/K), sum sq over D.
// grid = 2*B = 128 blocks, 256 threads.
// ---------------------------------------------------------------------------
__global__ __launch_bounds__(256) void feat_normsq_kernel(const float* __restrict__ meanpart,
                                                          float* __restrict__ normsq_out,
                                                          int ksplit) {
    const int tensor = blockIdx.x >> 6;
    const int b      = blockIdx.x & 63;
    const int tid    = threadIdx.x;

    float acc = 0.f;
    const float invK = 1.0f / (float)K;
    for (int d = tid; d < D; d += 256) {
        float m = 0.f;
        for (int sp = 0; sp < ksplit; ++sp)
            m += meanpart[((size_t)((tensor * ksplit + sp) * B + b)) * D + d];
        m *= invK;
        acc += m * m;
    }

    __shared__ float sh[256];
    sh[tid] = acc;
    __syncthreads();
    for (int s = 128; s > 0; s >>= 1) {
        if (tid < s) sh[tid] += sh[tid + s];
        __syncthreads();
    }
    if (tid == 0) normsq_out[(size_t)tensor * B + b] = sh[0];
}

// ---------------------------------------------------------------------------
// Kernel 3: loss_sup partials. grid = B*TT = 1600 blocks, 256 threads (250
// active). Thread (c4 = tid%25, tl = tid/25) reads rows tl+10*i, i=0..7 of its
// 80-row tile — all 16 float4 loads (8 gt + 8 cas) issued before use.
// ---------------------------------------------------------------------------
__global__ __launch_bounds__(256) void sup_kernel(const float* __restrict__ gt,
                                                  const float* __restrict__ cas,
                                                  float* __restrict__ ssq_out,
                                                  float* __restrict__ pos_out) {
    const int b    = blockIdx.x / TT;
    const int tile = blockIdx.x % TT;
    const int t0   = tile * TTILE;

    const int tid = threadIdx.x;
    const int c4  = tid % 25;      // float4 index within a row
    const int tl  = tid / 25;      // 0..9 active

    __shared__ float sh_ssq[C];
    __shared__ float sh_pos[C];
    if (tid < C) { sh_ssq[tid] = 0.f; sh_pos[tid] = 0.f; }
    __syncthreads();

    if (tl < 10) {
        const size_t base = ((size_t)b * T + (size_t)(t0 + tl)) * C + (size_t)c4 * 4;

        float4 g[8], q[8];
#pragma unroll
        for (int i = 0; i < 8; ++i) {
            size_t off = base + (size_t)(10 * i) * C;
            g[i] = *(const float4*)(gt + off);
            q[i] = *(const float4*)(cas + off);
        }

        float4 s0 = make_float4(0.f, 0.f, 0.f, 0.f);
        float4 s1 = make_float4(0.f, 0.f, 0.f, 0.f);
        float4 p0 = make_float4(0.f, 0.f, 0.f, 0.f);
        float4 p1 = make_float4(0.f, 0.f, 0.f, 0.f);

        auto acc = [](float gv, float qv, float& s, float& pc) {
            float pm = (gv > THRES) ? 1.f : 0.f;
            float dd = qv - pm;
            s += dd * dd;
            pc += pm;
        };
#pragma unroll
        for (int i = 0; i < 8; i += 2) {
            acc(g[i].x, q[i].x, s0.x, p0.x);
            acc(g[i].y, q[i].y, s0.y, p0.y);
            acc(g[i].z, q[i].z, s0.z, p0.z);
            acc(g[i].w, q[i].w, s0.w, p0.w);
            acc(g[i+1].x, q[i+1].x, s1.x, p1.x);
            acc(g[i+1].y, q[i+1].y, s1.y, p1.y);
            acc(g[i+1].z, q[i+1].z, s1.z, p1.z);
            acc(g[i+1].w, q[i+1].w, s1.w, p1.w);
        }

        const int c = c4 * 4;
        atomicAdd(&sh_ssq[c + 0], s0.x + s1.x);
        atomicAdd(&sh_ssq[c + 1], s0.y + s1.y);
        atomicAdd(&sh_ssq[c + 2], s0.z + s1.z);
        atomicAdd(&sh_ssq[c + 3], s0.w + s1.w);
        atomicAdd(&sh_pos[c + 0], p0.x + p1.x);
        atomicAdd(&sh_pos[c + 1], p0.y + p1.y);
        atomicAdd(&sh_pos[c + 2], p0.z + p1.z);
        atomicAdd(&sh_pos[c + 3], p0.w + p1.w);
    }
    __syncthreads();

    if (tid < C) {
        atomicAdd(&ssq_out[(size_t)b * C + tid], sh_ssq[tid]);
        atomicAdd(&pos_out[(size_t)b * C + tid], sh_pos[tid]);
    }
}

// ---------------------------------------------------------------------------
// Kernel 4: final scalar. 1 block, 256 threads, double accumulation.
// ---------------------------------------------------------------------------
__global__ __launch_bounds__(256) void final_kernel(const float* __restrict__ score_act,
                                                    const float* __restrict__ score_bkg,
                                                    const float* __restrict__ label,
                                                    const float* __restrict__ normsq,
                                                    const float* __restrict__ ssq_ws,
                                                    const float* __restrict__ pos_ws,
                                                    float* __restrict__ out) {
    const int tid = threadIdx.x;

    __shared__ float rowsum[B];
    if (tid < B) {
        float s = 0.f;
        const float* row = label + (size_t)tid * C;
        for (int c = 0; c < C; ++c) s += row[c];
        rowsum[tid] = s;
    }
    __syncthreads();

    double cls = 0.0, be = 0.0, sup = 0.0, cnt = 0.0;
    const float invC = 1.0f / (float)C;
    for (int i = tid; i < B * C; i += 256) {
        int bb = i / C;
        float y = label[i] / rowsum[bb];

        float p   = score_act[i];
        float lp  = fmaxf(logf(p), -100.0f);
        float l1p = fmaxf(logf(1.0f - p), -100.0f);
        cls += (double)(y * lp + (1.0f - y) * l1p);

        float q   = score_bkg[i];
        float lq  = fmaxf(logf(q), -100.0f);
        float l1q = fmaxf(logf(1.0f - q), -100.0f);
        be += (double)(invC * lq + (1.0f - invC) * l1q);

        float pos = pos_ws[i];
        if (pos > 0.5f) {
            sup += (double)sqrtf(ssq_ws[i]);
            cnt += 1.0;
        }
    }

    double um = 0.0;
    if (tid < B) {
        float na = sqrtf(normsq[tid]);
        float nb = sqrtf(normsq[B + tid]);
        float la = fmaxf(MARGIN - na, 0.0f);
        float t  = la + nb;
        um = (double)t * (double)t;
    }

    __shared__ double sd[256];
    auto block_reduce = [&](double v) -> double {
        sd[tid] = v;
        __syncthreads();
        for (int s = 128; s > 0; s >>= 1) {
            if (tid < s) sd[tid] += sd[tid + s];
            __syncthreads();
        }
        double r = sd[0];
        __syncthreads();
        return r;
    };

    double cls_t = block_reduce(cls);
    double be_t  = block_reduce(be);
    double sup_t = block_reduce(sup);
    double cnt_t = block_reduce(cnt);
    double um_t  = block_reduce(um);

    if (tid == 0) {
        double loss_cls = -cls_t / (double)(B * C);
        double loss_be  = -be_t / (double)(B * C);
        double loss_um  = um_t / (double)B;
        double loss_sup = sup_t / cnt_t;
        out[0] = (float)(loss_cls + (double)ALPHA * loss_um +
                         (double)BETA * loss_be + (double)LMBD * loss_sup);
    }
}

extern "C" void kernel_launch(void* const* d_in, const int* in_sizes, int n_in,
                              void* d_out, int out_size, void* d_ws, size_t ws_size,
                              hipStream_t stream) {
    const float* score_act = (const float*)d_in[0];
    const float* score_bkg = (const float*)d_in[1];
    const float* feat_act  = (const float*)d_in[2];
    const float* feat_bkg  = (const float*)d_in[3];
    const float* label     = (const float*)d_in[4];
    const float* gt        = (const float*)d_in[5];
    const float* cas       = (const float*)d_in[6];

    float* ws  = (float*)d_ws;
    float* out = (float*)d_out;

    // ksplit=8 needs ~8.45 MB of workspace; fall back to 4 (proven) if short.
    const size_t need8 = ((size_t)2 * 8 * B * D + 2 * B + 2 * (size_t)B * C) * sizeof(float);
    const int ksplit = (ws_size >= need8) ? 8 : 4;
    const int kq     = K / ksplit;

    float* meanpart = ws;
    float* normsq   = ws + (size_t)2 * ksplit * B * D;
    float* ssq      = normsq + 2 * B;
    float* pos      = ssq + (size_t)B * C;

    // zero only the atomic accumulation region (sup ssq + pos)
    hipMemsetAsync(ssq, 0, 2 * (size_t)B * C * sizeof(float), stream);

    feat_sum_kernel<<<2 * ksplit * 2 * B, 256, 0, stream>>>(feat_act, feat_bkg, meanpart,
                                                            ksplit, kq);
    feat_normsq_kernel<<<2 * B, 256, 0, stream>>>(meanpart, normsq, ksplit);
    sup_kernel<<<B * TT, 256, 0, stream>>>(gt, cas, ssq, pos);
    final_kernel<<<1, 256, 0, stream>>>(score_act, score_bkg, label, normsq, ssq, pos, out);
}

// Round 5
// 334.067 us; speedup vs baseline: 1.0522x; 1.0522x over previous
//
#include <hip/hip_runtime.h>
#include <math.h>

// Problem constants (from reference setup_inputs)
constexpr int B = 64, T = 2000, C = 100, K = 200, D = 2048;
constexpr float ALPHA = 0.0005f, BETA = 0.2f, LMBD = 1.0f, MARGIN = 100.0f, THRES = 0.5f;

constexpr int KSPLIT = 8;               // feat K split
constexpr int KQ     = K / KSPLIT;      // 25 rows per split
constexpr int TT     = 25;              // sup time tiles
constexpr int TTILE  = T / TT;          // 80 rows per tile

constexpr int FEAT_BLOCKS = 2 * KSPLIT * 2 * B;   // 2048 (tensor, split, dhalf, b)
constexpr int SUP_BLOCKS  = B * TT;               // 1600
constexpr int MEGA_BLOCKS = FEAT_BLOCKS + SUP_BLOCKS;  // 3648
constexpr int PAIRED      = 2 * SUP_BLOCKS;       // 3200: alternate feat/sup

// Workspace layout (floats): meanpart [2][KSPLIT][B][D], normsq [2][B],
// ssq [B][C], pos [B][C]
constexpr size_t WS_MEANPART = 0;
constexpr size_t WS_NORMSQ   = (size_t)2 * KSPLIT * B * D;
constexpr size_t WS_SUP_SSQ  = WS_NORMSQ + 2 * B;
constexpr size_t WS_SUP_POS  = WS_SUP_SSQ + (size_t)B * C;

// ---------------------------------------------------------------------------
// Mega kernel: feat partial-sum blocks and sup blocks interleaved in one
// dispatch so the HBM stream (feat_act) and L3 streams (feat_bkg, gt, cas)
// are serviced concurrently instead of in serial phases.
// ---------------------------------------------------------------------------
__global__ __launch_bounds__(256) void mega_kernel(const float* __restrict__ feat_act,
                                                   const float* __restrict__ feat_bkg,
                                                   const float* __restrict__ gt,
                                                   const float* __restrict__ cas,
                                                   float* __restrict__ ws) {
    const int id = blockIdx.x;
    const bool is_feat = (id < PAIRED) ? ((id & 1) == 0) : true;

    if (is_feat) {
        // ---------------- feat partial sums ----------------
        int t = (id < PAIRED) ? (id >> 1) : (SUP_BLOCKS + (id - PAIRED));
        const int b     = t & 63;  t >>= 6;
        const int dhalf = t & 1;   t >>= 1;
        const int split = t & 7;   t >>= 3;
        const int tensor = t;      // 0 or 1

        const float* __restrict__ feat = (tensor == 0) ? feat_act : feat_bkg;
        const float* p = feat + (size_t)b * K * D + (size_t)split * KQ * D
                         + (size_t)dhalf * 1024 + (size_t)threadIdx.x * 4;

        float4 a0 = make_float4(0.f, 0.f, 0.f, 0.f);
        float4 a1 = make_float4(0.f, 0.f, 0.f, 0.f);
        float4 a2 = make_float4(0.f, 0.f, 0.f, 0.f);
        float4 a3 = make_float4(0.f, 0.f, 0.f, 0.f);

        int k = 0;
        for (; k + 8 <= KQ; k += 8) {
            float4 v0 = *(const float4*)(p + (size_t)(k + 0) * D);
            float4 v1 = *(const float4*)(p + (size_t)(k + 1) * D);
            float4 v2 = *(const float4*)(p + (size_t)(k + 2) * D);
            float4 v3 = *(const float4*)(p + (size_t)(k + 3) * D);
            float4 v4 = *(const float4*)(p + (size_t)(k + 4) * D);
            float4 v5 = *(const float4*)(p + (size_t)(k + 5) * D);
            float4 v6 = *(const float4*)(p + (size_t)(k + 6) * D);
            float4 v7 = *(const float4*)(p + (size_t)(k + 7) * D);
            a0.x += v0.x; a0.y += v0.y; a0.z += v0.z; a0.w += v0.w;
            a1.x += v1.x; a1.y += v1.y; a1.z += v1.z; a1.w += v1.w;
            a2.x += v2.x; a2.y += v2.y; a2.z += v2.z; a2.w += v2.w;
            a3.x += v3.x; a3.y += v3.y; a3.z += v3.z; a3.w += v3.w;
            a0.x += v4.x; a0.y += v4.y; a0.z += v4.z; a0.w += v4.w;
            a1.x += v5.x; a1.y += v5.y; a1.z += v5.z; a1.w += v5.w;
            a2.x += v6.x; a2.y += v6.y; a2.z += v6.z; a2.w += v6.w;
            a3.x += v7.x; a3.y += v7.y; a3.z += v7.z; a3.w += v7.w;
        }
        for (; k < KQ; ++k) {
            float4 v = *(const float4*)(p + (size_t)k * D);
            a0.x += v.x; a0.y += v.y; a0.z += v.z; a0.w += v.w;
        }

        float4 s;
        s.x = (a0.x + a1.x) + (a2.x + a3.x);
        s.y = (a0.y + a1.y) + (a2.y + a3.y);
        s.z = (a0.z + a1.z) + (a2.z + a3.z);
        s.w = (a0.w + a1.w) + (a2.w + a3.w);

        float* dst = ws + WS_MEANPART
                     + ((size_t)((tensor * KSPLIT + split) * B + b)) * D
                     + (size_t)dhalf * 1024 + (size_t)threadIdx.x * 4;
        *(float4*)dst = s;
    } else {
        // ---------------- sup partials ----------------
        const int sid  = id >> 1;          // 0..1599
        const int b    = sid / TT;
        const int tile = sid % TT;
        const int t0   = tile * TTILE;

        const int tid = threadIdx.x;
        const int c4  = tid % 25;
        const int tl  = tid / 25;          // 0..9 active

        __shared__ float sh_ssq[C];
        __shared__ float sh_pos[C];
        if (tid < C) { sh_ssq[tid] = 0.f; sh_pos[tid] = 0.f; }
        __syncthreads();

        if (tl < 10) {
            const size_t base = ((size_t)b * T + (size_t)(t0 + tl)) * C + (size_t)c4 * 4;

            float4 g[8], q[8];
#pragma unroll
            for (int i = 0; i < 8; ++i) {
                size_t off = base + (size_t)(10 * i) * C;
                g[i] = *(const float4*)(gt + off);
                q[i] = *(const float4*)(cas + off);
            }

            float4 s0 = make_float4(0.f, 0.f, 0.f, 0.f);
            float4 s1 = make_float4(0.f, 0.f, 0.f, 0.f);
            float4 p0 = make_float4(0.f, 0.f, 0.f, 0.f);
            float4 p1 = make_float4(0.f, 0.f, 0.f, 0.f);

            auto acc = [](float gv, float qv, float& s, float& pc) {
                float pm = (gv > THRES) ? 1.f : 0.f;
                float dd = qv - pm;
                s += dd * dd;
                pc += pm;
            };
#pragma unroll
            for (int i = 0; i < 8; i += 2) {
                acc(g[i].x, q[i].x, s0.x, p0.x);
                acc(g[i].y, q[i].y, s0.y, p0.y);
                acc(g[i].z, q[i].z, s0.z, p0.z);
                acc(g[i].w, q[i].w, s0.w, p0.w);
                acc(g[i+1].x, q[i+1].x, s1.x, p1.x);
                acc(g[i+1].y, q[i+1].y, s1.y, p1.y);
                acc(g[i+1].z, q[i+1].z, s1.z, p1.z);
                acc(g[i+1].w, q[i+1].w, s1.w, p1.w);
            }

            const int c = c4 * 4;
            atomicAdd(&sh_ssq[c + 0], s0.x + s1.x);
            atomicAdd(&sh_ssq[c + 1], s0.y + s1.y);
            atomicAdd(&sh_ssq[c + 2], s0.z + s1.z);
            atomicAdd(&sh_ssq[c + 3], s0.w + s1.w);
            atomicAdd(&sh_pos[c + 0], p0.x + p1.x);
            atomicAdd(&sh_pos[c + 1], p0.y + p1.y);
            atomicAdd(&sh_pos[c + 2], p0.z + p1.z);
            atomicAdd(&sh_pos[c + 3], p0.w + p1.w);
        }
        __syncthreads();

        if (tid < C) {
            atomicAdd(&ws[WS_SUP_SSQ + (size_t)b * C + tid], sh_ssq[tid]);
            atomicAdd(&ws[WS_SUP_POS + (size_t)b * C + tid], sh_pos[tid]);
        }
    }
}

// ---------------------------------------------------------------------------
// Kernel 2: per-(tensor, b): combine KSPLIT partials, mean (/K), sum sq over D.
// grid = 2*B = 128 blocks, 256 threads.
// ---------------------------------------------------------------------------
__global__ __launch_bounds__(256) void feat_normsq_kernel(const float* __restrict__ ws,
                                                          float* __restrict__ normsq_out) {
    const int tensor = blockIdx.x >> 6;
    const int b      = blockIdx.x & 63;
    const int tid    = threadIdx.x;

    float acc = 0.f;
    const float invK = 1.0f / (float)K;
    for (int d = tid; d < D; d += 256) {
        float m = 0.f;
#pragma unroll
        for (int sp = 0; sp < KSPLIT; ++sp)
            m += ws[WS_MEANPART + ((size_t)((tensor * KSPLIT + sp) * B + b)) * D + d];
        m *= invK;
        acc += m * m;
    }

    __shared__ float sh[256];
    sh[tid] = acc;
    __syncthreads();
    for (int s = 128; s > 0; s >>= 1) {
        if (tid < s) sh[tid] += sh[tid + s];
        __syncthreads();
    }
    if (tid == 0) normsq_out[(size_t)tensor * B + b] = sh[0];
}

// ---------------------------------------------------------------------------
// Kernel 3: final scalar. 1 block, 256 threads, double accumulation.
// ---------------------------------------------------------------------------
__global__ __launch_bounds__(256) void final_kernel(const float* __restrict__ score_act,
                                                    const float* __restrict__ score_bkg,
                                                    const float* __restrict__ label,
                                                    const float* __restrict__ ws,
                                                    float* __restrict__ out) {
    const int tid = threadIdx.x;

    __shared__ float rowsum[B];
    if (tid < B) {
        float s = 0.f;
        const float* row = label + (size_t)tid * C;
        for (int c = 0; c < C; ++c) s += row[c];
        rowsum[tid] = s;
    }
    __syncthreads();

    const float* normsq = ws + WS_NORMSQ;
    const float* ssq_ws = ws + WS_SUP_SSQ;
    const float* pos_ws = ws + WS_SUP_POS;

    double cls = 0.0, be = 0.0, sup = 0.0, cnt = 0.0;
    const float invC = 1.0f / (float)C;
    for (int i = tid; i < B * C; i += 256) {
        int bb = i / C;
        float y = label[i] / rowsum[bb];

        float p   = score_act[i];
        float lp  = fmaxf(logf(p), -100.0f);
        float l1p = fmaxf(logf(1.0f - p), -100.0f);
        cls += (double)(y * lp + (1.0f - y) * l1p);

        float q   = score_bkg[i];
        float lq  = fmaxf(logf(q), -100.0f);
        float l1q = fmaxf(logf(1.0f - q), -100.0f);
        be += (double)(invC * lq + (1.0f - invC) * l1q);

        float pos = pos_ws[i];
        if (pos > 0.5f) {
            sup += (double)sqrtf(ssq_ws[i]);
            cnt += 1.0;
        }
    }

    double um = 0.0;
    if (tid < B) {
        float na = sqrtf(normsq[tid]);
        float nb = sqrtf(normsq[B + tid]);
        float la = fmaxf(MARGIN - na, 0.0f);
        float t  = la + nb;
        um = (double)t * (double)t;
    }

    __shared__ double sd[256];
    auto block_reduce = [&](double v) -> double {
        sd[tid] = v;
        __syncthreads();
        for (int s = 128; s > 0; s >>= 1) {
            if (tid < s) sd[tid] += sd[tid + s];
            __syncthreads();
        }
        double r = sd[0];
        __syncthreads();
        return r;
    };

    double cls_t = block_reduce(cls);
    double be_t  = block_reduce(be);
    double sup_t = block_reduce(sup);
    double cnt_t = block_reduce(cnt);
    double um_t  = block_reduce(um);

    if (tid == 0) {
        double loss_cls = -cls_t / (double)(B * C);
        double loss_be  = -be_t / (double)(B * C);
        double loss_um  = um_t / (double)B;
        double loss_sup = sup_t / cnt_t;
        out[0] = (float)(loss_cls + (double)ALPHA * loss_um +
                         (double)BETA * loss_be + (double)LMBD * loss_sup);
    }
}

extern "C" void kernel_launch(void* const* d_in, const int* in_sizes, int n_in,
                              void* d_out, int out_size, void* d_ws, size_t ws_size,
                              hipStream_t stream) {
    const float* score_act = (const float*)d_in[0];
    const float* score_bkg = (const float*)d_in[1];
    const float* feat_act  = (const float*)d_in[2];
    const float* feat_bkg  = (const float*)d_in[3];
    const float* label     = (const float*)d_in[4];
    const float* gt        = (const float*)d_in[5];
    const float* cas       = (const float*)d_in[6];

    float* ws  = (float*)d_ws;
    float* out = (float*)d_out;

    // zero only the atomic accumulation region (sup ssq + pos)
    hipMemsetAsync(ws + WS_SUP_SSQ, 0, 2 * (size_t)B * C * sizeof(float), stream);

    mega_kernel<<<MEGA_BLOCKS, 256, 0, stream>>>(feat_act, feat_bkg, gt, cas, ws);
    feat_normsq_kernel<<<2 * B, 256, 0, stream>>>(ws, ws + WS_NORMSQ);
    final_kernel<<<1, 256, 0, stream>>>(score_act, score_bkg, label, ws, out);
}